// Round 8
// baseline (277.453 us; speedup 1.0000x reference)
//
#include <hip/hip_runtime.h>
#include <math.h>

#define NTOK 2048   // t*b
#define DIM  1024
#define NHEAD 4
#define NKEY 512
#define DH   128    // = dim_head/2 (the per-p half-dim)
#define TK   32

typedef __attribute__((ext_vector_type(8))) short bf16x8;
typedef __attribute__((ext_vector_type(4))) float f32x4;

__device__ __forceinline__ unsigned short f2bf(float f) {
    unsigned int u = __float_as_uint(f);
    u += 0x7fff + ((u >> 16) & 1);
    return (unsigned short)(u >> 16);
}
__device__ __forceinline__ float bf2f(unsigned short h) {
    return __uint_as_float(((unsigned int)h) << 16);
}
// 3-way split: f ~= h + m + l, ~27 mantissa bits captured
__device__ __forceinline__ void split3(float f, unsigned short& h, unsigned short& m, unsigned short& l) {
    h = f2bf(f);
    float r1 = f - bf2f(h);
    m = f2bf(r1);
    l = f2bf(r1 - bf2f(m));
}
__device__ __forceinline__ void gll16(const void* g, void* l) {
    __builtin_amdgcn_global_load_lds((const __attribute__((address_space(1))) unsigned int*)g,
                                     (__attribute__((address_space(3))) unsigned int*)l, 16, 0, 0);
}
// split 8 consecutive fp32 (two float4) into 3 bf16x8 fragments
__device__ __forceinline__ void split8(const float (&vv)[8], bf16x8& h8, bf16x8& m8, bf16x8& l8) {
#pragma unroll
    for (int j = 0; j < 8; ++j) {
        unsigned short h, m, l;
        split3(vv[j], h, m, l);
        h8[j] = (short)h; m8[j] = (short)m; l8[j] = (short)l;
    }
}

// ---------------- prep: transpose+split Wq | split keys ----------------
__global__ __launch_bounds__(256) void k_prep(const float* __restrict__ Wq,
                                              const float* __restrict__ keys,
                                              unsigned short* __restrict__ W1,
                                              unsigned short* __restrict__ W2,
                                              unsigned short* __restrict__ W3,
                                              unsigned short* __restrict__ K1,
                                              unsigned short* __restrict__ K2,
                                              unsigned short* __restrict__ K3) {
    __shared__ float f[64][33];
    const int b = blockIdx.x, tid = threadIdx.x;
    if (b < 512) {                     // Wq transpose+split: 512 tiles of 64k x 32n
        const int kt = (b & 15) * 64, nt = (b >> 4) * 32;
#pragma unroll
        for (int i = 0; i < 8; ++i) {
            int idx = tid + i * 256;
            int nl = idx & 31, kl = idx >> 5;
            f[kl][nl] = Wq[(size_t)(kt + kl) * DIM + nt + nl];
        }
        __syncthreads();
#pragma unroll
        for (int i = 0; i < 2; ++i) {
            int idx = tid + i * 256;
            int k4 = (idx & 15) * 4, nl = idx >> 4;
            ushort4 hh, mm, ll;
            split3(f[k4 + 0][nl], hh.x, mm.x, ll.x);
            split3(f[k4 + 1][nl], hh.y, mm.y, ll.y);
            split3(f[k4 + 2][nl], hh.z, mm.z, ll.z);
            split3(f[k4 + 3][nl], hh.w, mm.w, ll.w);
            *(ushort4*)(W1 + (size_t)(nt + nl) * DIM + kt + k4) = hh;
            *(ushort4*)(W2 + (size_t)(nt + nl) * DIM + kt + k4) = mm;
            *(ushort4*)(W3 + (size_t)(nt + nl) * DIM + kt + k4) = ll;
        }
    } else {                           // keys: 4*512*2*128 floats = 131072 float4
        int i = (b - 512) * 256 + tid;
        float4 v = ((const float4*)keys)[i];
        ushort4 hh, mm, ll;
        split3(v.x, hh.x, mm.x, ll.x); split3(v.y, hh.y, mm.y, ll.y);
        split3(v.z, hh.z, mm.z, ll.z); split3(v.w, hh.w, mm.w, ll.w);
        ((ushort4*)K1)[i] = hh; ((ushort4*)K2)[i] = mm; ((ushort4*)K3)[i] = ll;
    }
}

// ---------------- MFMA GEMM: q = X * Wq; A split in-kernel from x fp32 ----------------
// tile 128(M) x 64(N), BK=64, 4 waves (2x2), wave computes 64x32
__global__ __launch_bounds__(256) void k_gemm(const float* __restrict__ X,
                                              const unsigned short* __restrict__ B1,
                                              const unsigned short* __restrict__ B2,
                                              const unsigned short* __restrict__ B3,
                                              float* __restrict__ C) {
    __shared__ alignas(16) unsigned short sA1[128 * 64];
    __shared__ alignas(16) unsigned short sA2[128 * 64];
    __shared__ alignas(16) unsigned short sA3[128 * 64];
    __shared__ alignas(16) unsigned short sB1[64 * 64];
    __shared__ alignas(16) unsigned short sB2[64 * 64];
    __shared__ alignas(16) unsigned short sB3[64 * 64];
    const int tid = threadIdx.x;
    const int lane = tid & 63, wid = tid >> 6;
    const int bm = blockIdx.x * 128, bn = blockIdx.y * 64;
    const int wr = (wid >> 1) * 64, wc = (wid & 1) * 32;
    f32x4 acc[4][2];
#pragma unroll
    for (int m = 0; m < 4; ++m)
#pragma unroll
        for (int n = 0; n < 2; ++n) acc[m][n] = (f32x4){0.f, 0.f, 0.f, 0.f};

    for (int kt = 0; kt < DIM; kt += 64) {
        // B via gll16 (pre-split, pre-swizzled source); LDS base wave-uniform
#pragma unroll
        for (int i = 0; i < 2; ++i) {
            int c = wid * 128 + i * 64 + lane;
            int row = c >> 3, kc = c & 7;
            int sk = (kc ^ (row & 7)) * 8;
            size_t ga = (size_t)(bn + row) * DIM + kt + sk;
            size_t lo = (size_t)(wid * 128 + i * 64) * 16;   // wave-uniform base
            gll16(B1 + ga, (char*)sB1 + lo);
            gll16(B2 + ga, (char*)sB2 + lo);
            gll16(B3 + ga, (char*)sB3 + lo);
        }
        // A: reg-stage x fp32, split3, swizzled ds_write (LDS[row][kc8^(row&7)] = x[row][kc8])
#pragma unroll
        for (int i = 0; i < 4; ++i) {
            int c = wid * 256 + i * 64 + lane;
            int row = c >> 3, kc8 = c & 7;
            const float4* src = (const float4*)(X + (size_t)(bm + row) * DIM + kt + kc8 * 8);
            float4 u0 = src[0], u1 = src[1];
            float vv[8] = {u0.x, u0.y, u0.z, u0.w, u1.x, u1.y, u1.z, u1.w};
            bf16x8 h8, m8, l8;
            split8(vv, h8, m8, l8);
            int dst = row * 64 + (kc8 ^ (row & 7)) * 8;
            *(bf16x8*)(sA1 + dst) = h8;
            *(bf16x8*)(sA2 + dst) = m8;
            *(bf16x8*)(sA3 + dst) = l8;
        }
        __syncthreads();
#pragma unroll
        for (int ks = 0; ks < 2; ++ks) {
            bf16x8 a1[4], a2[4], a3[4], b1[2], b2[2], b3[2];
#pragma unroll
            for (int m = 0; m < 4; ++m) {
                int row = wr + m * 16 + (lane & 15);
                int ch = (ks * 4 + (lane >> 4)) ^ (row & 7);
                int off = row * 64 + ch * 8;
                a1[m] = *(const bf16x8*)(sA1 + off);
                a2[m] = *(const bf16x8*)(sA2 + off);
                a3[m] = *(const bf16x8*)(sA3 + off);
            }
#pragma unroll
            for (int n = 0; n < 2; ++n) {
                int row = wc + n * 16 + (lane & 15);
                int ch = (ks * 4 + (lane >> 4)) ^ (row & 7);
                int off = row * 64 + ch * 8;
                b1[n] = *(const bf16x8*)(sB1 + off);
                b2[n] = *(const bf16x8*)(sB2 + off);
                b3[n] = *(const bf16x8*)(sB3 + off);
            }
#pragma unroll
            for (int m = 0; m < 4; ++m)
#pragma unroll
                for (int n = 0; n < 2; ++n) {
                    acc[m][n] = __builtin_amdgcn_mfma_f32_16x16x32_bf16(a1[m], b1[n], acc[m][n], 0, 0, 0);
                    acc[m][n] = __builtin_amdgcn_mfma_f32_16x16x32_bf16(a1[m], b2[n], acc[m][n], 0, 0, 0);
                    acc[m][n] = __builtin_amdgcn_mfma_f32_16x16x32_bf16(a2[m], b1[n], acc[m][n], 0, 0, 0);
                    acc[m][n] = __builtin_amdgcn_mfma_f32_16x16x32_bf16(a2[m], b2[n], acc[m][n], 0, 0, 0);
                    acc[m][n] = __builtin_amdgcn_mfma_f32_16x16x32_bf16(a1[m], b3[n], acc[m][n], 0, 0, 0);
                    acc[m][n] = __builtin_amdgcn_mfma_f32_16x16x32_bf16(a3[m], b1[n], acc[m][n], 0, 0, 0);
                }
        }
        __syncthreads();
    }
#pragma unroll
    for (int m = 0; m < 4; ++m)
#pragma unroll
        for (int n = 0; n < 2; ++n)
#pragma unroll
            for (int j = 0; j < 4; ++j) {
                int row = bm + wr + m * 16 + (lane >> 4) * 4 + j;
                int col = bn + wc + n * 16 + (lane & 15);
                C[(size_t)row * DIM + col] = acc[m][n][j];
            }
}

// ---------------- per-row LN stats: mu, inv (deterministic reduction) ----------------
__global__ __launch_bounds__(256) void k_stats(const float* __restrict__ Q,
                                               float2* __restrict__ stats) {
    const int row = blockIdx.x, tid = threadIdx.x;
    float4 v = *(const float4*)(Q + (size_t)row * DIM + tid * 4);
    float s  = v.x + v.y + v.z + v.w;
    float s2 = v.x * v.x + v.y * v.y + v.z * v.z + v.w * v.w;
#pragma unroll
    for (int off = 32; off > 0; off >>= 1) {
        s  += __shfl_down(s, off);
        s2 += __shfl_down(s2, off);
    }
    __shared__ float ps[4], ps2[4];
    const int wid = tid >> 6, lane = tid & 63;
    if (lane == 0) { ps[wid] = s; ps2[wid] = s2; }
    __syncthreads();
    if (tid == 0) {
        s  = ps[0] + ps[1] + ps[2] + ps[3];
        s2 = ps2[0] + ps2[1] + ps2[2] + ps2[3];
        const float mu  = s * (1.0f / DIM);
        const float var = s2 * (1.0f / DIM) - mu * mu;
        stats[row] = make_float2(mu, rsqrtf(var + 1e-5f));
    }
}

// ---------------- MFMA dots; Q normalized+split in-kernel from q fp32 ----------------
// tile 64(tokens) x 64(keys), K=128, 4 waves (2x2), wave computes 32x32
__global__ __launch_bounds__(256) void k_dotsF(const float* __restrict__ Q,
                                               const float2* __restrict__ stats,
                                               const float* __restrict__ gamma,
                                               const float* __restrict__ beta,
                                               const unsigned short* __restrict__ K1,
                                               const unsigned short* __restrict__ K2,
                                               const unsigned short* __restrict__ K3,
                                               float* __restrict__ D) {
    __shared__ alignas(16) unsigned short sA1[64 * 128];
    __shared__ alignas(16) unsigned short sA2[64 * 128];
    __shared__ alignas(16) unsigned short sA3[64 * 128];
    __shared__ alignas(16) unsigned short sB1[64 * 128];
    __shared__ alignas(16) unsigned short sB2[64 * 128];
    __shared__ alignas(16) unsigned short sB3[64 * 128];
    const int tid = threadIdx.x;
    const int lane = tid & 63, wid = tid >> 6;
    const int bm = blockIdx.x * 64, bn = blockIdx.y * 64;
    const int hp = blockIdx.z, h = hp >> 1, p = hp & 1;
    const int qoff = p * 512 + h * 128;
    const size_t kbase = (size_t)h * (NKEY * 2 * DH) + (size_t)p * DH;
#pragma unroll
    for (int i = 0; i < 4; ++i) {
        int c = wid * 256 + i * 64 + lane;
        int row = c >> 4, kc8 = c & 15;
        // K via gll16 (pre-split, pre-swizzled source); LDS base wave-uniform
        int sk = (kc8 ^ (row & 15)) * 8;
        size_t ka = kbase + (size_t)(bn + row) * (2 * DH) + sk;
        size_t lo = (size_t)(wid * 256 + i * 64) * 16;       // wave-uniform base
        gll16(K1 + ka, (char*)sB1 + lo);
        gll16(K2 + ka, (char*)sB2 + lo);
        gll16(K3 + ka, (char*)sB3 + lo);
        // Q: reg-stage fp32, apply LN, split3, swizzled ds_write
        float2 st = stats[bm + row];
        int colbase = qoff + kc8 * 8;
        const float4* qs = (const float4*)(Q + (size_t)(bm + row) * DIM + colbase);
        float4 u0 = qs[0], u1 = qs[1];
        const float4* g4 = (const float4*)(gamma + colbase);
        const float4* b4 = (const float4*)(beta + colbase);
        float4 g0 = g4[0], g1 = g4[1], e0 = b4[0], e1 = b4[1];
        float vv[8] = {
            (u0.x - st.x) * st.y * g0.x + e0.x, (u0.y - st.x) * st.y * g0.y + e0.y,
            (u0.z - st.x) * st.y * g0.z + e0.z, (u0.w - st.x) * st.y * g0.w + e0.w,
            (u1.x - st.x) * st.y * g1.x + e1.x, (u1.y - st.x) * st.y * g1.y + e1.y,
            (u1.z - st.x) * st.y * g1.z + e1.z, (u1.w - st.x) * st.y * g1.w + e1.w };
        bf16x8 h8, m8, l8;
        split8(vv, h8, m8, l8);
        int dst = row * 128 + (kc8 ^ (row & 15)) * 8;
        *(bf16x8*)(sA1 + dst) = h8;
        *(bf16x8*)(sA2 + dst) = m8;
        *(bf16x8*)(sA3 + dst) = l8;
    }
    __syncthreads();
    const int wr = (wid >> 1) * 32, wc = (wid & 1) * 32;
    f32x4 acc[2][2];
#pragma unroll
    for (int m = 0; m < 2; ++m)
#pragma unroll
        for (int n = 0; n < 2; ++n) acc[m][n] = (f32x4){0.f, 0.f, 0.f, 0.f};
#pragma unroll
    for (int ks = 0; ks < 4; ++ks) {
        bf16x8 a1[2], a2[2], a3[2], b1[2], b2[2], b3[2];
#pragma unroll
        for (int m = 0; m < 2; ++m) {
            int row = wr + m * 16 + (lane & 15);
            int ch = (ks * 4 + (lane >> 4)) ^ (row & 15);
            int off = row * 128 + ch * 8;
            a1[m] = *(const bf16x8*)(sA1 + off);
            a2[m] = *(const bf16x8*)(sA2 + off);
            a3[m] = *(const bf16x8*)(sA3 + off);
        }
#pragma unroll
        for (int n = 0; n < 2; ++n) {
            int row = wc + n * 16 + (lane & 15);
            int ch = (ks * 4 + (lane >> 4)) ^ (row & 15);
            int off = row * 128 + ch * 8;
            b1[n] = *(const bf16x8*)(sB1 + off);
            b2[n] = *(const bf16x8*)(sB2 + off);
            b3[n] = *(const bf16x8*)(sB3 + off);
        }
#pragma unroll
        for (int m = 0; m < 2; ++m)
#pragma unroll
            for (int n = 0; n < 2; ++n) {
                acc[m][n] = __builtin_amdgcn_mfma_f32_16x16x32_bf16(a1[m], b1[n], acc[m][n], 0, 0, 0);
                acc[m][n] = __builtin_amdgcn_mfma_f32_16x16x32_bf16(a1[m], b2[n], acc[m][n], 0, 0, 0);
                acc[m][n] = __builtin_amdgcn_mfma_f32_16x16x32_bf16(a2[m], b1[n], acc[m][n], 0, 0, 0);
                acc[m][n] = __builtin_amdgcn_mfma_f32_16x16x32_bf16(a2[m], b2[n], acc[m][n], 0, 0, 0);
                acc[m][n] = __builtin_amdgcn_mfma_f32_16x16x32_bf16(a1[m], b3[n], acc[m][n], 0, 0, 0);
                acc[m][n] = __builtin_amdgcn_mfma_f32_16x16x32_bf16(a3[m], b1[n], acc[m][n], 0, 0, 0);
            }
    }
#pragma unroll
    for (int m = 0; m < 2; ++m)
#pragma unroll
        for (int n = 0; n < 2; ++n)
#pragma unroll
            for (int j = 0; j < 4; ++j) {
                int row = bm + wr + m * 16 + (lane >> 4) * 4 + j;
                int col = bn + wc + n * 16 + (lane & 15);
                D[(size_t)row * 4096 + h * 1024 + p * 512 + col] = acc[m][n][j];
            }
}

// ---- bisection: find tau with 32 <= #{v >= tau} <= 64 (wave-uniform result) ----
template<int NV>
__device__ __forceinline__ bool bisect_tau(const float (&v)[NV], float& tau_out, int& c_out) {
    float lo = v[0], hi = v[0];
#pragma unroll
    for (int i = 1; i < NV; ++i) { lo = fminf(lo, v[i]); hi = fmaxf(hi, v[i]); }
#pragma unroll
    for (int off = 1; off < 64; off <<= 1) {
        lo = fminf(lo, __shfl_xor(lo, off));
        hi = fmaxf(hi, __shfl_xor(hi, off));
    }
    float tau = 0.5f * (lo + hi);
    for (int it = 0; it < 24; ++it) {
        int cl = 0;
#pragma unroll
        for (int i = 0; i < NV; ++i) cl += (v[i] >= tau) ? 1 : 0;
#pragma unroll
        for (int off = 1; off < 64; off <<= 1) cl += __shfl_xor(cl, off);
        if (cl >= 32 && cl <= 64) { tau_out = tau; c_out = cl; return true; }
        if (cl < 32) hi = tau; else lo = tau;
        float nt = 0.5f * (lo + hi);
        if (nt == tau || nt == lo || nt == hi) break;   // bracket exhausted -> fallback
        tau = nt;
    }
    return false;
}

// ---- bitonic-64 across lanes, sort (v desc, n asc); pads sink ----
__device__ __forceinline__ void bitonic64(float& sv, int& sn, int lane) {
#pragma unroll
    for (int k = 2; k <= 64; k <<= 1) {
#pragma unroll
        for (int j = k >> 1; j >= 1; j >>= 1) {
            float ov = __shfl_xor(sv, j);
            int   on = __shfl_xor(sn, j);
            bool lower   = (lane & j) == 0;
            bool descseg = (lane & k) == 0;
            bool keepwin = (lower == descseg);
            bool iwin = (sv > ov) || (sv == ov && sn < on);
            if (keepwin != iwin) { sv = ov; sn = on; }
        }
    }
}

// ---------------- fused topk + gather: one block per token ----------------
__global__ __launch_bounds__(256) void k_topk_gather(const float* __restrict__ D,
                                                     const float* __restrict__ V,
                                                     float* __restrict__ out) {
    const int tid = threadIdx.x;
    const int wid = tid >> 6, lane = tid & 63;
    const int token = blockIdx.x;
    const int h = wid;
    __shared__ float s1[NHEAD][TK], s2[NHEAD][TK], wv[NHEAD][TK];
    __shared__ int   i1[NHEAD][TK], i2[NHEAD][TK], cc[NHEAD][TK];
    __shared__ float candV[NHEAD][64];
    __shared__ int   candN[NHEAD][64];
    __shared__ float wgt[128];
    __shared__ int   gidx[128];

    const size_t base = (size_t)token * 4096 + (size_t)h * 1024;
    float v1[8], v2[8];
#pragma unroll
    for (int i = 0; i < 8; ++i) {
        v1[i] = D[base + lane + (i << 6)];
        v2[i] = D[base + 512 + lane + (i << 6)];
    }

    // ---- select top-32 of v1 / v2 via bisect+compact+bitonic (fallback: extraction) ----
#pragma unroll
    for (int half = 0; half < 2; ++half) {
        float (&vv)[8] = half ? v2 : v1;
        float* sO = half ? &s2[h][0] : &s1[h][0];
        int*   iO = half ? &i2[h][0] : &i1[h][0];
        float tau; int c;
        if (bisect_tau<8>(vv, tau, c)) {
            int cum = 0;
#pragma unroll
            for (int i = 0; i < 8; ++i) {
                bool f = (vv[i] >= tau);
                unsigned long long bal = __ballot(f);
                int slot = cum + __popcll(bal & ((1ull << lane) - 1ull));
                if (f) { candV[h][slot] = vv[i]; candN[h][slot] = lane + (i << 6); }
                cum += __popcll(bal);
            }
            asm volatile("s_waitcnt lgkmcnt(0)" ::: "memory");
            float sv = (lane < c) ? candV[h][lane] : -INFINITY;
            int   sn = (lane < c) ? candN[h][lane] : 0x7FFFFFFF;
            bitonic64(sv, sn, lane);
            if (lane < TK) { sO[lane] = sv; iO[lane] = sn; }
        } else {
            // fallback: serial extraction (exact, rare)
            for (int it = 0; it < TK; ++it) {
                float bv = vv[0]; int bi = 0;
#pragma unroll
                for (int i = 1; i < 8; ++i) if (vv[i] > bv) { bv = vv[i]; bi = i; }
                int bn = lane + (bi << 6);
#pragma unroll
                for (int off = 1; off < 64; off <<= 1) {
                    float ov = __shfl_xor(bv, off);
                    int   on = __shfl_xor(bn, off);
                    if (ov > bv || (ov == bv && on < bn)) { bv = ov; bn = on; }
                }
#pragma unroll
                for (int i = 0; i < 8; ++i)
                    if (bn == lane + (i << 6)) vv[i] = -INFINITY;
                if (lane == 0) { sO[it] = bv; iO[it] = bn; }
            }
        }
    }

    // ---- combine: top-32 of 1024 pairwise sums, c-index tie-break, fused softmax ----
    float cv[16];
#pragma unroll
    for (int s = 0; s < 16; ++s) {
        int c = lane + (s << 6);
        cv[s] = s1[h][c >> 5] + s2[h][c & 31];
    }
    {
        float tau; int c;
        if (bisect_tau<16>(cv, tau, c)) {
            int cum = 0;
#pragma unroll
            for (int s = 0; s < 16; ++s) {
                bool f = (cv[s] >= tau);
                unsigned long long bal = __ballot(f);
                int slot = cum + __popcll(bal & ((1ull << lane) - 1ull));
                if (f) { candV[h][slot] = cv[s]; candN[h][slot] = lane + (s << 6); }
                cum += __popcll(bal);
            }
            asm volatile("s_waitcnt lgkmcnt(0)" ::: "memory");
            float sv = (lane < c) ? candV[h][lane] : -INFINITY;
            int   sn = (lane < c) ? candN[h][lane] : 0x7FFFFFFF;
            bitonic64(sv, sn, lane);
            float m = __shfl(sv, 0);
            float w = (lane < TK) ? expf(sv - m) : 0.0f;
            float sum = w;
#pragma unroll
            for (int off = 1; off < 64; off <<= 1) sum += __shfl_xor(sum, off);
            if (lane < TK) {
                wgt[h * TK + lane]  = w / sum;
                gidx[h * TK + lane] = i1[h][sn >> 5] * NKEY + i2[h][sn & 31];
            }
        } else {
            float m = 0.f, sum = 0.f;
            for (int it = 0; it < TK; ++it) {
                float bv = cv[0]; int bs = 0;
#pragma unroll
                for (int s = 1; s < 16; ++s) if (cv[s] > bv) { bv = cv[s]; bs = s; }
                int bc = lane + (bs << 6);
#pragma unroll
                for (int off = 1; off < 64; off <<= 1) {
                    float ov = __shfl_xor(bv, off);
                    int   oc = __shfl_xor(bc, off);
                    if (ov > bv || (ov == bv && oc < bc)) { bv = ov; bc = oc; }
                }
#pragma unroll
                for (int s = 0; s < 16; ++s)
                    if (bc == lane + (s << 6)) cv[s] = -INFINITY;
                if (it == 0) m = bv;
                float w = expf(bv - m);
                sum += w;
                if (lane == 0) { wv[h][it] = w; cc[h][it] = bc; }
            }
            if (lane < TK) {
                int c2 = cc[h][lane];
                wgt[h * TK + lane]  = wv[h][lane] / sum;
                gidx[h * TK + lane] = i1[h][c2 >> 5] * NKEY + i2[h][c2 & 31];
            }
        }
    }
    __syncthreads();

    // ---- phase 2: gather + weighted sum ----
    const int col = tid * 4;
    float4 acc = make_float4(0.f, 0.f, 0.f, 0.f);
#pragma unroll 8
    for (int j = 0; j < 128; ++j) {
        const float4 v = *(const float4*)(V + (size_t)gidx[j] * DIM + col);
        const float wj = wgt[j];
        acc.x = fmaf(wj, v.x, acc.x);
        acc.y = fmaf(wj, v.y, acc.y);
        acc.z = fmaf(wj, v.z, acc.z);
        acc.w = fmaf(wj, v.w, acc.w);
    }
    *(float4*)(out + (size_t)token * DIM + col) = acc;
}

extern "C" void kernel_launch(void* const* d_in, const int* in_sizes, int n_in,
                              void* d_out, int out_size, void* d_ws, size_t ws_size,
                              hipStream_t stream) {
    const float* x      = (const float*)d_in[0];
    const float* Wq     = (const float*)d_in[1];
    const float* gamma  = (const float*)d_in[2];
    const float* beta   = (const float*)d_in[3];
    const float* keys   = (const float*)d_in[4];
    const float* values = (const float*)d_in[5];

    char* w = (char*)d_ws;
    float* D = (float*)w;                          // 0..32 MB  (dots output)
    float* q = (float*)(w + ((size_t)32 << 20));   // 32..40 MB (q fp32 -- DISJOINT from D)
    unsigned short* W1 = (unsigned short*)(w + ((size_t)46 << 20));
    unsigned short* W2 = (unsigned short*)(w + ((size_t)48 << 20));
    unsigned short* W3 = (unsigned short*)(w + ((size_t)50 << 20));
    float2*         st = (float2*)        (w + ((size_t)52 << 20));
    unsigned short* K1 = (unsigned short*)(w + ((size_t)64 << 20));
    unsigned short* K2 = (unsigned short*)(w + ((size_t)65 << 20));
    unsigned short* K3 = (unsigned short*)(w + ((size_t)66 << 20));

    k_prep<<<1024, 256, 0, stream>>>(Wq, keys, W1, W2, W3, K1, K2, K3);
    k_gemm<<<dim3(16, 16), 256, 0, stream>>>(x, W1, W2, W3, q);
    k_stats<<<NTOK, 256, 0, stream>>>(q, st);
    k_dotsF<<<dim3(32, 8, 8), 256, 0, stream>>>(q, st, gamma, beta, K1, K2, K3, D);
    k_topk_gather<<<NTOK, 256, 0, stream>>>(D, values, (float*)d_out);
}

// Round 9
// 247.862 us; speedup vs baseline: 1.1194x; 1.1194x over previous
//
#include <hip/hip_runtime.h>
#include <math.h>

#define NTOK 2048   // t*b
#define DIM  1024
#define NHEAD 4
#define NKEY 512
#define DH   128    // = dim_head/2 (the per-p half-dim)
#define TK   32

typedef __attribute__((ext_vector_type(8))) short bf16x8;
typedef __attribute__((ext_vector_type(4))) float f32x4;

__device__ __forceinline__ unsigned short f2bf(float f) {
    unsigned int u = __float_as_uint(f);
    u += 0x7fff + ((u >> 16) & 1);
    return (unsigned short)(u >> 16);
}
__device__ __forceinline__ float bf2f(unsigned short h) {
    return __uint_as_float(((unsigned int)h) << 16);
}
// 3-way split: f ~= h + m + l, ~27 mantissa bits captured
__device__ __forceinline__ void split3(float f, unsigned short& h, unsigned short& m, unsigned short& l) {
    h = f2bf(f);
    float r1 = f - bf2f(h);
    m = f2bf(r1);
    l = f2bf(r1 - bf2f(m));
}
__device__ __forceinline__ void gll16(const void* g, void* l) {
    __builtin_amdgcn_global_load_lds((const __attribute__((address_space(1))) unsigned int*)g,
                                     (__attribute__((address_space(3))) unsigned int*)l, 16, 0, 0);
}

// ---------------- fused prep: split x | transpose+split Wq | split keys ----------------
__global__ __launch_bounds__(256) void k_prep(const float* __restrict__ x,
                                              const float* __restrict__ Wq,
                                              const float* __restrict__ keys,
                                              unsigned short* __restrict__ X1,
                                              unsigned short* __restrict__ X2,
                                              unsigned short* __restrict__ X3,
                                              unsigned short* __restrict__ W1,
                                              unsigned short* __restrict__ W2,
                                              unsigned short* __restrict__ W3,
                                              unsigned short* __restrict__ K1,
                                              unsigned short* __restrict__ K2,
                                              unsigned short* __restrict__ K3) {
    __shared__ float f[64][33];
    const int b = blockIdx.x, tid = threadIdx.x;
    if (b < 2048) {                    // x: 2048*1024 floats = 524288 float4
        int i = b * 256 + tid;
        float4 v = ((const float4*)x)[i];
        ushort4 hh, mm, ll;
        split3(v.x, hh.x, mm.x, ll.x); split3(v.y, hh.y, mm.y, ll.y);
        split3(v.z, hh.z, mm.z, ll.z); split3(v.w, hh.w, mm.w, ll.w);
        ((ushort4*)X1)[i] = hh; ((ushort4*)X2)[i] = mm; ((ushort4*)X3)[i] = ll;
    } else if (b < 2560) {             // Wq transpose+split: 512 tiles of 64k x 32n
        const int ff = b - 2048;
        const int kt = (ff & 15) * 64, nt = (ff >> 4) * 32;
#pragma unroll
        for (int i = 0; i < 8; ++i) {
            int idx = tid + i * 256;
            int nl = idx & 31, kl = idx >> 5;
            f[kl][nl] = Wq[(size_t)(kt + kl) * DIM + nt + nl];
        }
        __syncthreads();
#pragma unroll
        for (int i = 0; i < 2; ++i) {
            int idx = tid + i * 256;
            int k4 = (idx & 15) * 4, nl = idx >> 4;
            ushort4 hh, mm, ll;
            split3(f[k4 + 0][nl], hh.x, mm.x, ll.x);
            split3(f[k4 + 1][nl], hh.y, mm.y, ll.y);
            split3(f[k4 + 2][nl], hh.z, mm.z, ll.z);
            split3(f[k4 + 3][nl], hh.w, mm.w, ll.w);
            *(ushort4*)(W1 + (size_t)(nt + nl) * DIM + kt + k4) = hh;
            *(ushort4*)(W2 + (size_t)(nt + nl) * DIM + kt + k4) = mm;
            *(ushort4*)(W3 + (size_t)(nt + nl) * DIM + kt + k4) = ll;
        }
    } else {                           // keys: 4*512*2*128 floats = 131072 float4
        int i = (b - 2560) * 256 + tid;
        float4 v = ((const float4*)keys)[i];
        ushort4 hh, mm, ll;
        split3(v.x, hh.x, mm.x, ll.x); split3(v.y, hh.y, mm.y, ll.y);
        split3(v.z, hh.z, mm.z, ll.z); split3(v.w, hh.w, mm.w, ll.w);
        ((ushort4*)K1)[i] = hh; ((ushort4*)K2)[i] = mm; ((ushort4*)K3)[i] = ll;
    }
}

// ---------------- MFMA GEMM: q = X * Wq, 3-way split, 6 products ----------------
// tile 64(M) x 64(N), BK=64, 48 KB LDS -> 3 blocks/CU, grid 32x16 = 512 blocks
__global__ __launch_bounds__(256) void k_gemm(const unsigned short* __restrict__ A1,
                                              const unsigned short* __restrict__ A2,
                                              const unsigned short* __restrict__ A3,
                                              const unsigned short* __restrict__ B1,
                                              const unsigned short* __restrict__ B2,
                                              const unsigned short* __restrict__ B3,
                                              float* __restrict__ C) {
    __shared__ alignas(16) unsigned short sA1[64 * 64];
    __shared__ alignas(16) unsigned short sA2[64 * 64];
    __shared__ alignas(16) unsigned short sA3[64 * 64];
    __shared__ alignas(16) unsigned short sB1[64 * 64];
    __shared__ alignas(16) unsigned short sB2[64 * 64];
    __shared__ alignas(16) unsigned short sB3[64 * 64];
    const int tid = threadIdx.x;
    const int lane = tid & 63, wid = tid >> 6;
    const int bm = blockIdx.x * 64, bn = blockIdx.y * 64;
    const int wr = (wid >> 1) * 32, wc = (wid & 1) * 32;
    f32x4 acc[2][2];
#pragma unroll
    for (int m = 0; m < 2; ++m)
#pragma unroll
        for (int n = 0; n < 2; ++n) acc[m][n] = (f32x4){0.f, 0.f, 0.f, 0.f};

    for (int kt = 0; kt < DIM; kt += 64) {
        // A,B: 64x64 bf16 = 512 16B-chunks per array; wave handles 128 (2 x 64)
#pragma unroll
        for (int i = 0; i < 2; ++i) {
            int c = wid * 128 + i * 64 + lane;
            int row = c >> 3, kc = c & 7;
            int sk = (kc ^ (row & 7)) * 8;                 // pre-swizzled source chunk
            size_t lo = (size_t)(wid * 128 + i * 64) * 16; // wave-uniform LDS base
            size_t gaA = (size_t)(bm + row) * DIM + kt + sk;
            size_t gaB = (size_t)(bn + row) * DIM + kt + sk;
            gll16(A1 + gaA, (char*)sA1 + lo);
            gll16(A2 + gaA, (char*)sA2 + lo);
            gll16(A3 + gaA, (char*)sA3 + lo);
            gll16(B1 + gaB, (char*)sB1 + lo);
            gll16(B2 + gaB, (char*)sB2 + lo);
            gll16(B3 + gaB, (char*)sB3 + lo);
        }
        __syncthreads();
#pragma unroll
        for (int ks = 0; ks < 2; ++ks) {
            bf16x8 a1[2], a2[2], a3[2], b1[2], b2[2], b3[2];
#pragma unroll
            for (int m = 0; m < 2; ++m) {
                int row = wr + m * 16 + (lane & 15);
                int ch = (ks * 4 + (lane >> 4)) ^ (row & 7);
                int off = row * 64 + ch * 8;
                a1[m] = *(const bf16x8*)(sA1 + off);
                a2[m] = *(const bf16x8*)(sA2 + off);
                a3[m] = *(const bf16x8*)(sA3 + off);
            }
#pragma unroll
            for (int n = 0; n < 2; ++n) {
                int row = wc + n * 16 + (lane & 15);
                int ch = (ks * 4 + (lane >> 4)) ^ (row & 7);
                int off = row * 64 + ch * 8;
                b1[n] = *(const bf16x8*)(sB1 + off);
                b2[n] = *(const bf16x8*)(sB2 + off);
                b3[n] = *(const bf16x8*)(sB3 + off);
            }
#pragma unroll
            for (int m = 0; m < 2; ++m)
#pragma unroll
                for (int n = 0; n < 2; ++n) {
                    acc[m][n] = __builtin_amdgcn_mfma_f32_16x16x32_bf16(a1[m], b1[n], acc[m][n], 0, 0, 0);
                    acc[m][n] = __builtin_amdgcn_mfma_f32_16x16x32_bf16(a1[m], b2[n], acc[m][n], 0, 0, 0);
                    acc[m][n] = __builtin_amdgcn_mfma_f32_16x16x32_bf16(a2[m], b1[n], acc[m][n], 0, 0, 0);
                    acc[m][n] = __builtin_amdgcn_mfma_f32_16x16x32_bf16(a2[m], b2[n], acc[m][n], 0, 0, 0);
                    acc[m][n] = __builtin_amdgcn_mfma_f32_16x16x32_bf16(a1[m], b3[n], acc[m][n], 0, 0, 0);
                    acc[m][n] = __builtin_amdgcn_mfma_f32_16x16x32_bf16(a3[m], b1[n], acc[m][n], 0, 0, 0);
                }
        }
        __syncthreads();
    }
#pragma unroll
    for (int m = 0; m < 2; ++m)
#pragma unroll
        for (int n = 0; n < 2; ++n)
#pragma unroll
            for (int j = 0; j < 4; ++j) {
                int row = bm + wr + m * 16 + (lane >> 4) * 4 + j;
                int col = bn + wc + n * 16 + (lane & 15);
                C[(size_t)row * DIM + col] = acc[m][n][j];
            }
}

// ---------------- LayerNorm: q fp32 -> 3x bf16 ----------------
__global__ __launch_bounds__(256) void k_ln(const float* __restrict__ Q,
                                            const float* __restrict__ gamma,
                                            const float* __restrict__ beta,
                                            unsigned short* __restrict__ q1,
                                            unsigned short* __restrict__ q2,
                                            unsigned short* __restrict__ q3) {
    const int row = blockIdx.x, tid = threadIdx.x;
    float4 v = *(const float4*)(Q + (size_t)row * DIM + tid * 4);
    float s  = v.x + v.y + v.z + v.w;
    float s2 = v.x * v.x + v.y * v.y + v.z * v.z + v.w * v.w;
#pragma unroll
    for (int off = 32; off > 0; off >>= 1) {
        s  += __shfl_down(s, off);
        s2 += __shfl_down(s2, off);
    }
    __shared__ float ps[4], ps2[4];
    const int wid = tid >> 6, lane = tid & 63;
    if (lane == 0) { ps[wid] = s; ps2[wid] = s2; }
    __syncthreads();
    s  = ps[0] + ps[1] + ps[2] + ps[3];
    s2 = ps2[0] + ps2[1] + ps2[2] + ps2[3];
    const float mu  = s * (1.0f / DIM);
    const float var = s2 * (1.0f / DIM) - mu * mu;
    const float inv = rsqrtf(var + 1e-5f);
    float4 g  = *(const float4*)(gamma + tid * 4);
    float4 be = *(const float4*)(beta + tid * 4);
    float o0 = (v.x - mu) * inv * g.x + be.x;
    float o1 = (v.y - mu) * inv * g.y + be.y;
    float o2 = (v.z - mu) * inv * g.z + be.z;
    float o3 = (v.w - mu) * inv * g.w + be.w;
    ushort4 hh, mm, ll;
    split3(o0, hh.x, mm.x, ll.x); split3(o1, hh.y, mm.y, ll.y);
    split3(o2, hh.z, mm.z, ll.z); split3(o3, hh.w, mm.w, ll.w);
    *(ushort4*)(q1 + (size_t)row * DIM + tid * 4) = hh;
    *(ushort4*)(q2 + (size_t)row * DIM + tid * 4) = mm;
    *(ushort4*)(q3 + (size_t)row * DIM + tid * 4) = ll;
}

// ---------------- MFMA dots over K=128, 3-way split, 6 products ----------------
__global__ __launch_bounds__(256) void k_dotsM(const unsigned short* __restrict__ Q1,
                                               const unsigned short* __restrict__ Q2,
                                               const unsigned short* __restrict__ Q3,
                                               const unsigned short* __restrict__ K1,
                                               const unsigned short* __restrict__ K2,
                                               const unsigned short* __restrict__ K3,
                                               float* __restrict__ D) {
    __shared__ alignas(16) unsigned short sA1[64 * 128];
    __shared__ alignas(16) unsigned short sA2[64 * 128];
    __shared__ alignas(16) unsigned short sA3[64 * 128];
    __shared__ alignas(16) unsigned short sB1[64 * 128];
    __shared__ alignas(16) unsigned short sB2[64 * 128];
    __shared__ alignas(16) unsigned short sB3[64 * 128];
    const int tid = threadIdx.x;
    const int lane = tid & 63, wid = tid >> 6;
    const int bm = blockIdx.x * 64, bn = blockIdx.y * 64;
    const int hp = blockIdx.z, h = hp >> 1, p = hp & 1;
    const int qoff = p * 512 + h * 128;
    const size_t kbase = (size_t)h * (NKEY * 2 * DH) + (size_t)p * DH;
#pragma unroll
    for (int i = 0; i < 4; ++i) {
        int c = wid * 256 + i * 64 + lane;
        int row = c >> 4, kc = c & 15;
        int sk = (kc ^ (row & 15)) * 8;
        size_t qa = (size_t)(bm + row) * DIM + qoff + sk;
        size_t ka = kbase + (size_t)(bn + row) * (2 * DH) + sk;
        size_t lo = (size_t)(wid * 256 + i * 64) * 16;
        gll16(Q1 + qa, (char*)sA1 + lo);
        gll16(Q2 + qa, (char*)sA2 + lo);
        gll16(Q3 + qa, (char*)sA3 + lo);
        gll16(K1 + ka, (char*)sB1 + lo);
        gll16(K2 + ka, (char*)sB2 + lo);
        gll16(K3 + ka, (char*)sB3 + lo);
    }
    __syncthreads();
    const int wr = (wid >> 1) * 32, wc = (wid & 1) * 32;
    f32x4 acc[2][2];
#pragma unroll
    for (int m = 0; m < 2; ++m)
#pragma unroll
        for (int n = 0; n < 2; ++n) acc[m][n] = (f32x4){0.f, 0.f, 0.f, 0.f};
#pragma unroll
    for (int ks = 0; ks < 4; ++ks) {
        bf16x8 a1[2], a2[2], a3[2], b1[2], b2[2], b3[2];
#pragma unroll
        for (int m = 0; m < 2; ++m) {
            int row = wr + m * 16 + (lane & 15);
            int ch = (ks * 4 + (lane >> 4)) ^ (row & 15);
            int off = row * 128 + ch * 8;
            a1[m] = *(const bf16x8*)(sA1 + off);
            a2[m] = *(const bf16x8*)(sA2 + off);
            a3[m] = *(const bf16x8*)(sA3 + off);
        }
#pragma unroll
        for (int n = 0; n < 2; ++n) {
            int row = wc + n * 16 + (lane & 15);
            int ch = (ks * 4 + (lane >> 4)) ^ (row & 15);
            int off = row * 128 + ch * 8;
            b1[n] = *(const bf16x8*)(sB1 + off);
            b2[n] = *(const bf16x8*)(sB2 + off);
            b3[n] = *(const bf16x8*)(sB3 + off);
        }
#pragma unroll
        for (int m = 0; m < 2; ++m)
#pragma unroll
            for (int n = 0; n < 2; ++n) {
                acc[m][n] = __builtin_amdgcn_mfma_f32_16x16x32_bf16(a1[m], b1[n], acc[m][n], 0, 0, 0);
                acc[m][n] = __builtin_amdgcn_mfma_f32_16x16x32_bf16(a1[m], b2[n], acc[m][n], 0, 0, 0);
                acc[m][n] = __builtin_amdgcn_mfma_f32_16x16x32_bf16(a2[m], b1[n], acc[m][n], 0, 0, 0);
                acc[m][n] = __builtin_amdgcn_mfma_f32_16x16x32_bf16(a2[m], b2[n], acc[m][n], 0, 0, 0);
                acc[m][n] = __builtin_amdgcn_mfma_f32_16x16x32_bf16(a1[m], b3[n], acc[m][n], 0, 0, 0);
                acc[m][n] = __builtin_amdgcn_mfma_f32_16x16x32_bf16(a3[m], b1[n], acc[m][n], 0, 0, 0);
            }
    }
#pragma unroll
    for (int m = 0; m < 2; ++m)
#pragma unroll
        for (int n = 0; n < 2; ++n)
#pragma unroll
            for (int j = 0; j < 4; ++j) {
                int row = bm + wr + m * 16 + (lane >> 4) * 4 + j;
                int col = bn + wc + n * 16 + (lane & 15);
                D[(size_t)row * 4096 + h * 1024 + p * 512 + col] = acc[m][n][j];
            }
}

// ---- bisection: find tau with 32 <= #{v >= tau} <= 64 (wave-uniform result) ----
template<int NV>
__device__ __forceinline__ bool bisect_tau(const float (&v)[NV], float& tau_out, int& c_out) {
    float lo = v[0], hi = v[0];
#pragma unroll
    for (int i = 1; i < NV; ++i) { lo = fminf(lo, v[i]); hi = fmaxf(hi, v[i]); }
#pragma unroll
    for (int off = 1; off < 64; off <<= 1) {
        lo = fminf(lo, __shfl_xor(lo, off));
        hi = fmaxf(hi, __shfl_xor(hi, off));
    }
    float tau = 0.5f * (lo + hi);
    for (int it = 0; it < 24; ++it) {
        int cl = 0;
#pragma unroll
        for (int i = 0; i < NV; ++i) cl += (v[i] >= tau) ? 1 : 0;
#pragma unroll
        for (int off = 1; off < 64; off <<= 1) cl += __shfl_xor(cl, off);
        if (cl >= 32 && cl <= 64) { tau_out = tau; c_out = cl; return true; }
        if (cl < 32) hi = tau; else lo = tau;
        float nt = 0.5f * (lo + hi);
        if (nt == tau || nt == lo || nt == hi) break;   // bracket exhausted -> fallback
        tau = nt;
    }
    return false;
}

// ---- bitonic-64 across lanes, sort (v desc, n asc); pads sink ----
__device__ __forceinline__ void bitonic64(float& sv, int& sn, int lane) {
#pragma unroll
    for (int k = 2; k <= 64; k <<= 1) {
#pragma unroll
        for (int j = k >> 1; j >= 1; j >>= 1) {
            float ov = __shfl_xor(sv, j);
            int   on = __shfl_xor(sn, j);
            bool lower   = (lane & j) == 0;
            bool descseg = (lane & k) == 0;
            bool keepwin = (lower == descseg);
            bool iwin = (sv > ov) || (sv == ov && sn < on);
            if (keepwin != iwin) { sv = ov; sn = on; }
        }
    }
}

// ---------------- fused topk + gather: one block per token ----------------
__global__ __launch_bounds__(256) void k_topk_gather(const float* __restrict__ D,
                                                     const float* __restrict__ V,
                                                     float* __restrict__ out) {
    const int tid = threadIdx.x;
    const int wid = tid >> 6, lane = tid & 63;
    const int token = blockIdx.x;
    const int h = wid;
    __shared__ float s1[NHEAD][TK], s2[NHEAD][TK], wv[NHEAD][TK];
    __shared__ int   i1[NHEAD][TK], i2[NHEAD][TK], cc[NHEAD][TK];
    __shared__ float candV[NHEAD][64];
    __shared__ int   candN[NHEAD][64];
    __shared__ float wgt[128];
    __shared__ int   gidx[128];

    const size_t base = (size_t)token * 4096 + (size_t)h * 1024;
    float v1[8], v2[8];
#pragma unroll
    for (int i = 0; i < 8; ++i) {
        v1[i] = D[base + lane + (i << 6)];
        v2[i] = D[base + 512 + lane + (i << 6)];
    }

    // ---- select top-32 of v1 / v2 via bisect+compact+bitonic (fallback: extraction) ----
#pragma unroll
    for (int half = 0; half < 2; ++half) {
        float (&vv)[8] = half ? v2 : v1;
        float* sO = half ? &s2[h][0] : &s1[h][0];
        int*   iO = half ? &i2[h][0] : &i1[h][0];
        float tau; int c;
        if (bisect_tau<8>(vv, tau, c)) {
            int cum = 0;
#pragma unroll
            for (int i = 0; i < 8; ++i) {
                bool f = (vv[i] >= tau);
                unsigned long long bal = __ballot(f);
                int slot = cum + __popcll(bal & ((1ull << lane) - 1ull));
                if (f) { candV[h][slot] = vv[i]; candN[h][slot] = lane + (i << 6); }
                cum += __popcll(bal);
            }
            asm volatile("s_waitcnt lgkmcnt(0)" ::: "memory");
            float sv = (lane < c) ? candV[h][lane] : -INFINITY;
            int   sn = (lane < c) ? candN[h][lane] : 0x7FFFFFFF;
            bitonic64(sv, sn, lane);
            if (lane < TK) { sO[lane] = sv; iO[lane] = sn; }
        } else {
            // fallback: serial extraction (exact, rare)
            for (int it = 0; it < TK; ++it) {
                float bv = vv[0]; int bi = 0;
#pragma unroll
                for (int i = 1; i < 8; ++i) if (vv[i] > bv) { bv = vv[i]; bi = i; }
                int bn = lane + (bi << 6);
#pragma unroll
                for (int off = 1; off < 64; off <<= 1) {
                    float ov = __shfl_xor(bv, off);
                    int   on = __shfl_xor(bn, off);
                    if (ov > bv || (ov == bv && on < bn)) { bv = ov; bn = on; }
                }
#pragma unroll
                for (int i = 0; i < 8; ++i)
                    if (bn == lane + (i << 6)) vv[i] = -INFINITY;
                if (lane == 0) { sO[it] = bv; iO[it] = bn; }
            }
        }
    }

    // ---- combine: top-32 of 1024 pairwise sums, c-index tie-break, fused softmax ----
    float cv[16];
#pragma unroll
    for (int s = 0; s < 16; ++s) {
        int c = lane + (s << 6);
        cv[s] = s1[h][c >> 5] + s2[h][c & 31];
    }
    {
        float tau; int c;
        if (bisect_tau<16>(cv, tau, c)) {
            int cum = 0;
#pragma unroll
            for (int s = 0; s < 16; ++s) {
                bool f = (cv[s] >= tau);
                unsigned long long bal = __ballot(f);
                int slot = cum + __popcll(bal & ((1ull << lane) - 1ull));
                if (f) { candV[h][slot] = cv[s]; candN[h][slot] = lane + (s << 6); }
                cum += __popcll(bal);
            }
            asm volatile("s_waitcnt lgkmcnt(0)" ::: "memory");
            float sv = (lane < c) ? candV[h][lane] : -INFINITY;
            int   sn = (lane < c) ? candN[h][lane] : 0x7FFFFFFF;
            bitonic64(sv, sn, lane);
            float m = __shfl(sv, 0);
            float w = (lane < TK) ? expf(sv - m) : 0.0f;
            float sum = w;
#pragma unroll
            for (int off = 1; off < 64; off <<= 1) sum += __shfl_xor(sum, off);
            if (lane < TK) {
                wgt[h * TK + lane]  = w / sum;
                gidx[h * TK + lane] = i1[h][sn >> 5] * NKEY + i2[h][sn & 31];
            }
        } else {
            float m = 0.f, sum = 0.f;
            for (int it = 0; it < TK; ++it) {
                float bv = cv[0]; int bs = 0;
#pragma unroll
                for (int s = 1; s < 16; ++s) if (cv[s] > bv) { bv = cv[s]; bs = s; }
                int bc = lane + (bs << 6);
#pragma unroll
                for (int off = 1; off < 64; off <<= 1) {
                    float ov = __shfl_xor(bv, off);
                    int   oc = __shfl_xor(bc, off);
                    if (ov > bv || (ov == bv && oc < bc)) { bv = ov; bc = oc; }
                }
#pragma unroll
                for (int s = 0; s < 16; ++s)
                    if (bc == lane + (s << 6)) cv[s] = -INFINITY;
                if (it == 0) m = bv;
                float w = expf(bv - m);
                sum += w;
                if (lane == 0) { wv[h][it] = w; cc[h][it] = bc; }
            }
            if (lane < TK) {
                int c2 = cc[h][lane];
                wgt[h * TK + lane]  = wv[h][lane] / sum;
                gidx[h * TK + lane] = i1[h][c2 >> 5] * NKEY + i2[h][c2 & 31];
            }
        }
    }
    __syncthreads();

    // ---- phase 2: gather + weighted sum ----
    const int col = tid * 4;
    float4 acc = make_float4(0.f, 0.f, 0.f, 0.f);
#pragma unroll 8
    for (int j = 0; j < 128; ++j) {
        const float4 v = *(const float4*)(V + (size_t)gidx[j] * DIM + col);
        const float wj = wgt[j];
        acc.x = fmaf(wj, v.x, acc.x);
        acc.y = fmaf(wj, v.y, acc.y);
        acc.z = fmaf(wj, v.z, acc.z);
        acc.w = fmaf(wj, v.w, acc.w);
    }
    *(float4*)(out + (size_t)token * DIM + col) = acc;
}

extern "C" void kernel_launch(void* const* d_in, const int* in_sizes, int n_in,
                              void* d_out, int out_size, void* d_ws, size_t ws_size,
                              hipStream_t stream) {
    const float* x      = (const float*)d_in[0];
    const float* Wq     = (const float*)d_in[1];
    const float* gamma  = (const float*)d_in[2];
    const float* beta   = (const float*)d_in[3];
    const float* keys   = (const float*)d_in[4];
    const float* values = (const float*)d_in[5];

    char* w = (char*)d_ws;
    float* D = (float*)w;                          // 32 MB (first 8 MB alias q fp32; q dead before dots writes D)
    float* q = D;
    unsigned short* X1 = (unsigned short*)(w + ((size_t)34 << 20));
    unsigned short* X2 = (unsigned short*)(w + ((size_t)38 << 20));
    unsigned short* X3 = (unsigned short*)(w + ((size_t)42 << 20));
    unsigned short* W1 = (unsigned short*)(w + ((size_t)46 << 20));
    unsigned short* W2 = (unsigned short*)(w + ((size_t)48 << 20));
    unsigned short* W3 = (unsigned short*)(w + ((size_t)50 << 20));
    unsigned short* q1 = (unsigned short*)(w + ((size_t)52 << 20));
    unsigned short* q2 = (unsigned short*)(w + ((size_t)56 << 20));
    unsigned short* q3 = (unsigned short*)(w + ((size_t)60 << 20));
    unsigned short* K1 = (unsigned short*)(w + ((size_t)64 << 20));
    unsigned short* K2 = (unsigned short*)(w + ((size_t)65 << 20));
    unsigned short* K3 = (unsigned short*)(w + ((size_t)66 << 20));

    k_prep<<<3072, 256, 0, stream>>>(x, Wq, keys, X1, X2, X3, W1, W2, W3, K1, K2, K3);
    k_gemm<<<dim3(32, 16), 256, 0, stream>>>(X1, X2, X3, W1, W2, W3, q);
    k_ln<<<NTOK, 256, 0, stream>>>(q, gamma, beta, q1, q2, q3);
    k_dotsM<<<dim3(32, 8, 8), 256, 0, stream>>>(q1, q2, q3, K1, K2, K3, D);
    k_topk_gather<<<NTOK, 256, 0, stream>>>(D, values, (float*)d_out);
}

// Round 10
// 242.010 us; speedup vs baseline: 1.1465x; 1.0242x over previous
//
#include <hip/hip_runtime.h>
#include <math.h>

#define NTOK 2048   // t*b
#define DIM  1024
#define NHEAD 4
#define NKEY 512
#define DH   128    // = dim_head/2 (the per-p half-dim)
#define TK   32

typedef __attribute__((ext_vector_type(8))) short bf16x8;
typedef __attribute__((ext_vector_type(4))) float f32x4;

__device__ __forceinline__ unsigned short f2bf(float f) {
    unsigned int u = __float_as_uint(f);
    u += 0x7fff + ((u >> 16) & 1);
    return (unsigned short)(u >> 16);
}
__device__ __forceinline__ float bf2f(unsigned short h) {
    return __uint_as_float(((unsigned int)h) << 16);
}
// 3-way split: f ~= h + m + l, ~27 mantissa bits captured
__device__ __forceinline__ void split3(float f, unsigned short& h, unsigned short& m, unsigned short& l) {
    h = f2bf(f);
    float r1 = f - bf2f(h);
    m = f2bf(r1);
    l = f2bf(r1 - bf2f(m));
}
__device__ __forceinline__ void gll16(const void* g, void* l) {
    __builtin_amdgcn_global_load_lds((const __attribute__((address_space(1))) unsigned int*)g,
                                     (__attribute__((address_space(3))) unsigned int*)l, 16, 0, 0);
}

// ---------------- fused prep: split x | transpose+split Wq | split keys ----------------
__global__ __launch_bounds__(256) void k_prep(const float* __restrict__ x,
                                              const float* __restrict__ Wq,
                                              const float* __restrict__ keys,
                                              unsigned short* __restrict__ X1,
                                              unsigned short* __restrict__ X2,
                                              unsigned short* __restrict__ X3,
                                              unsigned short* __restrict__ W1,
                                              unsigned short* __restrict__ W2,
                                              unsigned short* __restrict__ W3,
                                              unsigned short* __restrict__ K1,
                                              unsigned short* __restrict__ K2,
                                              unsigned short* __restrict__ K3) {
    __shared__ float f[64][33];
    const int b = blockIdx.x, tid = threadIdx.x;
    if (b < 2048) {                    // x: 2048*1024 floats = 524288 float4
        int i = b * 256 + tid;
        float4 v = ((const float4*)x)[i];
        ushort4 hh, mm, ll;
        split3(v.x, hh.x, mm.x, ll.x); split3(v.y, hh.y, mm.y, ll.y);
        split3(v.z, hh.z, mm.z, ll.z); split3(v.w, hh.w, mm.w, ll.w);
        ((ushort4*)X1)[i] = hh; ((ushort4*)X2)[i] = mm; ((ushort4*)X3)[i] = ll;
    } else if (b < 2560) {             // Wq transpose+split: 512 tiles of 64k x 32n
        const int ff = b - 2048;
        const int kt = (ff & 15) * 64, nt = (ff >> 4) * 32;
#pragma unroll
        for (int i = 0; i < 8; ++i) {
            int idx = tid + i * 256;
            int nl = idx & 31, kl = idx >> 5;
            f[kl][nl] = Wq[(size_t)(kt + kl) * DIM + nt + nl];
        }
        __syncthreads();
#pragma unroll
        for (int i = 0; i < 2; ++i) {
            int idx = tid + i * 256;
            int k4 = (idx & 15) * 4, nl = idx >> 4;
            ushort4 hh, mm, ll;
            split3(f[k4 + 0][nl], hh.x, mm.x, ll.x);
            split3(f[k4 + 1][nl], hh.y, mm.y, ll.y);
            split3(f[k4 + 2][nl], hh.z, mm.z, ll.z);
            split3(f[k4 + 3][nl], hh.w, mm.w, ll.w);
            *(ushort4*)(W1 + (size_t)(nt + nl) * DIM + kt + k4) = hh;
            *(ushort4*)(W2 + (size_t)(nt + nl) * DIM + kt + k4) = mm;
            *(ushort4*)(W3 + (size_t)(nt + nl) * DIM + kt + k4) = ll;
        }
    } else {                           // keys: 4*512*2*128 floats = 131072 float4
        int i = (b - 2560) * 256 + tid;
        float4 v = ((const float4*)keys)[i];
        ushort4 hh, mm, ll;
        split3(v.x, hh.x, mm.x, ll.x); split3(v.y, hh.y, mm.y, ll.y);
        split3(v.z, hh.z, mm.z, ll.z); split3(v.w, hh.w, mm.w, ll.w);
        ((ushort4*)K1)[i] = hh; ((ushort4*)K2)[i] = mm; ((ushort4*)K3)[i] = ll;
    }
}

// ---------------- MFMA GEMM: q = X * Wq, 3-way split, 6 products ----------------
// tile 64(M) x 64(N), BK=64, 48 KB LDS -> 3 blocks/CU, grid 32x16 = 512 blocks
__global__ __launch_bounds__(256) void k_gemm(const unsigned short* __restrict__ A1,
                                              const unsigned short* __restrict__ A2,
                                              const unsigned short* __restrict__ A3,
                                              const unsigned short* __restrict__ B1,
                                              const unsigned short* __restrict__ B2,
                                              const unsigned short* __restrict__ B3,
                                              float* __restrict__ C) {
    __shared__ alignas(16) unsigned short sA1[64 * 64];
    __shared__ alignas(16) unsigned short sA2[64 * 64];
    __shared__ alignas(16) unsigned short sA3[64 * 64];
    __shared__ alignas(16) unsigned short sB1[64 * 64];
    __shared__ alignas(16) unsigned short sB2[64 * 64];
    __shared__ alignas(16) unsigned short sB3[64 * 64];
    const int tid = threadIdx.x;
    const int lane = tid & 63, wid = tid >> 6;
    const int bm = blockIdx.x * 64, bn = blockIdx.y * 64;
    const int wr = (wid >> 1) * 32, wc = (wid & 1) * 32;
    f32x4 acc[2][2];
#pragma unroll
    for (int m = 0; m < 2; ++m)
#pragma unroll
        for (int n = 0; n < 2; ++n) acc[m][n] = (f32x4){0.f, 0.f, 0.f, 0.f};

    for (int kt = 0; kt < DIM; kt += 64) {
        // A,B: 64x64 bf16 = 512 16B-chunks per array; wave handles 128 (2 x 64)
#pragma unroll
        for (int i = 0; i < 2; ++i) {
            int c = wid * 128 + i * 64 + lane;
            int row = c >> 3, kc = c & 7;
            int sk = (kc ^ (row & 7)) * 8;                 // pre-swizzled source chunk
            size_t lo = (size_t)(wid * 128 + i * 64) * 16; // wave-uniform LDS base
            size_t gaA = (size_t)(bm + row) * DIM + kt + sk;
            size_t gaB = (size_t)(bn + row) * DIM + kt + sk;
            gll16(A1 + gaA, (char*)sA1 + lo);
            gll16(A2 + gaA, (char*)sA2 + lo);
            gll16(A3 + gaA, (char*)sA3 + lo);
            gll16(B1 + gaB, (char*)sB1 + lo);
            gll16(B2 + gaB, (char*)sB2 + lo);
            gll16(B3 + gaB, (char*)sB3 + lo);
        }
        __syncthreads();
#pragma unroll
        for (int ks = 0; ks < 2; ++ks) {
            bf16x8 a1[2], a2[2], a3[2], b1[2], b2[2], b3[2];
#pragma unroll
            for (int m = 0; m < 2; ++m) {
                int row = wr + m * 16 + (lane & 15);
                int ch = (ks * 4 + (lane >> 4)) ^ (row & 7);
                int off = row * 64 + ch * 8;
                a1[m] = *(const bf16x8*)(sA1 + off);
                a2[m] = *(const bf16x8*)(sA2 + off);
                a3[m] = *(const bf16x8*)(sA3 + off);
            }
#pragma unroll
            for (int n = 0; n < 2; ++n) {
                int row = wc + n * 16 + (lane & 15);
                int ch = (ks * 4 + (lane >> 4)) ^ (row & 7);
                int off = row * 64 + ch * 8;
                b1[n] = *(const bf16x8*)(sB1 + off);
                b2[n] = *(const bf16x8*)(sB2 + off);
                b3[n] = *(const bf16x8*)(sB3 + off);
            }
#pragma unroll
            for (int m = 0; m < 2; ++m)
#pragma unroll
                for (int n = 0; n < 2; ++n) {
                    acc[m][n] = __builtin_amdgcn_mfma_f32_16x16x32_bf16(a1[m], b1[n], acc[m][n], 0, 0, 0);
                    acc[m][n] = __builtin_amdgcn_mfma_f32_16x16x32_bf16(a1[m], b2[n], acc[m][n], 0, 0, 0);
                    acc[m][n] = __builtin_amdgcn_mfma_f32_16x16x32_bf16(a2[m], b1[n], acc[m][n], 0, 0, 0);
                    acc[m][n] = __builtin_amdgcn_mfma_f32_16x16x32_bf16(a2[m], b2[n], acc[m][n], 0, 0, 0);
                    acc[m][n] = __builtin_amdgcn_mfma_f32_16x16x32_bf16(a1[m], b3[n], acc[m][n], 0, 0, 0);
                    acc[m][n] = __builtin_amdgcn_mfma_f32_16x16x32_bf16(a3[m], b1[n], acc[m][n], 0, 0, 0);
                }
        }
        __syncthreads();
    }
#pragma unroll
    for (int m = 0; m < 2; ++m)
#pragma unroll
        for (int n = 0; n < 2; ++n)
#pragma unroll
            for (int j = 0; j < 4; ++j) {
                int row = bm + wr + m * 16 + (lane >> 4) * 4 + j;
                int col = bn + wc + n * 16 + (lane & 15);
                C[(size_t)row * DIM + col] = acc[m][n][j];
            }
}

// ---------------- LayerNorm: q fp32 -> 3x bf16 ----------------
__global__ __launch_bounds__(256) void k_ln(const float* __restrict__ Q,
                                            const float* __restrict__ gamma,
                                            const float* __restrict__ beta,
                                            unsigned short* __restrict__ q1,
                                            unsigned short* __restrict__ q2,
                                            unsigned short* __restrict__ q3) {
    const int row = blockIdx.x, tid = threadIdx.x;
    float4 v = *(const float4*)(Q + (size_t)row * DIM + tid * 4);
    float s  = v.x + v.y + v.z + v.w;
    float s2 = v.x * v.x + v.y * v.y + v.z * v.z + v.w * v.w;
#pragma unroll
    for (int off = 32; off > 0; off >>= 1) {
        s  += __shfl_down(s, off);
        s2 += __shfl_down(s2, off);
    }
    __shared__ float ps[4], ps2[4];
    const int wid = tid >> 6, lane = tid & 63;
    if (lane == 0) { ps[wid] = s; ps2[wid] = s2; }
    __syncthreads();
    s  = ps[0] + ps[1] + ps[2] + ps[3];
    s2 = ps2[0] + ps2[1] + ps2[2] + ps2[3];
    const float mu  = s * (1.0f / DIM);
    const float var = s2 * (1.0f / DIM) - mu * mu;
    const float inv = rsqrtf(var + 1e-5f);
    float4 g  = *(const float4*)(gamma + tid * 4);
    float4 be = *(const float4*)(beta + tid * 4);
    float o0 = (v.x - mu) * inv * g.x + be.x;
    float o1 = (v.y - mu) * inv * g.y + be.y;
    float o2 = (v.z - mu) * inv * g.z + be.z;
    float o3 = (v.w - mu) * inv * g.w + be.w;
    ushort4 hh, mm, ll;
    split3(o0, hh.x, mm.x, ll.x); split3(o1, hh.y, mm.y, ll.y);
    split3(o2, hh.z, mm.z, ll.z); split3(o3, hh.w, mm.w, ll.w);
    *(ushort4*)(q1 + (size_t)row * DIM + tid * 4) = hh;
    *(ushort4*)(q2 + (size_t)row * DIM + tid * 4) = mm;
    *(ushort4*)(q3 + (size_t)row * DIM + tid * 4) = ll;
}

// ---------------- MFMA dots over K=128, 3-way split, 6 products ----------------
// tile 64(tokens) x 64(keys), BK=64 two-step staging, 48 KB LDS -> 3 blocks/CU
__global__ __launch_bounds__(256) void k_dotsM(const unsigned short* __restrict__ Q1,
                                               const unsigned short* __restrict__ Q2,
                                               const unsigned short* __restrict__ Q3,
                                               const unsigned short* __restrict__ K1,
                                               const unsigned short* __restrict__ K2,
                                               const unsigned short* __restrict__ K3,
                                               float* __restrict__ D) {
    __shared__ alignas(16) unsigned short sA1[64 * 64];
    __shared__ alignas(16) unsigned short sA2[64 * 64];
    __shared__ alignas(16) unsigned short sA3[64 * 64];
    __shared__ alignas(16) unsigned short sB1[64 * 64];
    __shared__ alignas(16) unsigned short sB2[64 * 64];
    __shared__ alignas(16) unsigned short sB3[64 * 64];
    const int tid = threadIdx.x;
    const int lane = tid & 63, wid = tid >> 6;
    const int bm = blockIdx.x * 64, bn = blockIdx.y * 64;
    const int hp = blockIdx.z, h = hp >> 1, p = hp & 1;
    const int qoff = p * 512 + h * 128;
    const size_t kbase = (size_t)h * (NKEY * 2 * DH) + (size_t)p * DH;
    const int wr = (wid >> 1) * 32, wc = (wid & 1) * 32;
    f32x4 acc[2][2];
#pragma unroll
    for (int m = 0; m < 2; ++m)
#pragma unroll
        for (int n = 0; n < 2; ++n) acc[m][n] = (f32x4){0.f, 0.f, 0.f, 0.f};

#pragma unroll
    for (int kt = 0; kt < 2 * 64; kt += 64) {          // two BK=64 halves of K=128
#pragma unroll
        for (int i = 0; i < 2; ++i) {
            int c = wid * 128 + i * 64 + lane;
            int row = c >> 3, kc = c & 7;
            int sk = (kc ^ (row & 7)) * 8;                 // pre-swizzled source chunk
            size_t lo = (size_t)(wid * 128 + i * 64) * 16; // wave-uniform LDS base
            size_t qa = (size_t)(bm + row) * DIM + qoff + kt + sk;
            size_t ka = kbase + (size_t)(bn + row) * (2 * DH) + kt + sk;
            gll16(Q1 + qa, (char*)sA1 + lo);
            gll16(Q2 + qa, (char*)sA2 + lo);
            gll16(Q3 + qa, (char*)sA3 + lo);
            gll16(K1 + ka, (char*)sB1 + lo);
            gll16(K2 + ka, (char*)sB2 + lo);
            gll16(K3 + ka, (char*)sB3 + lo);
        }
        __syncthreads();
#pragma unroll
        for (int ks = 0; ks < 2; ++ks) {
            bf16x8 a1[2], a2[2], a3[2], b1[2], b2[2], b3[2];
#pragma unroll
            for (int m = 0; m < 2; ++m) {
                int row = wr + m * 16 + (lane & 15);
                int ch = (ks * 4 + (lane >> 4)) ^ (row & 7);
                int off = row * 64 + ch * 8;
                a1[m] = *(const bf16x8*)(sA1 + off);
                a2[m] = *(const bf16x8*)(sA2 + off);
                a3[m] = *(const bf16x8*)(sA3 + off);
            }
#pragma unroll
            for (int n = 0; n < 2; ++n) {
                int row = wc + n * 16 + (lane & 15);
                int ch = (ks * 4 + (lane >> 4)) ^ (row & 7);
                int off = row * 64 + ch * 8;
                b1[n] = *(const bf16x8*)(sB1 + off);
                b2[n] = *(const bf16x8*)(sB2 + off);
                b3[n] = *(const bf16x8*)(sB3 + off);
            }
#pragma unroll
            for (int m = 0; m < 2; ++m)
#pragma unroll
                for (int n = 0; n < 2; ++n) {
                    acc[m][n] = __builtin_amdgcn_mfma_f32_16x16x32_bf16(a1[m], b1[n], acc[m][n], 0, 0, 0);
                    acc[m][n] = __builtin_amdgcn_mfma_f32_16x16x32_bf16(a1[m], b2[n], acc[m][n], 0, 0, 0);
                    acc[m][n] = __builtin_amdgcn_mfma_f32_16x16x32_bf16(a2[m], b1[n], acc[m][n], 0, 0, 0);
                    acc[m][n] = __builtin_amdgcn_mfma_f32_16x16x32_bf16(a2[m], b2[n], acc[m][n], 0, 0, 0);
                    acc[m][n] = __builtin_amdgcn_mfma_f32_16x16x32_bf16(a1[m], b3[n], acc[m][n], 0, 0, 0);
                    acc[m][n] = __builtin_amdgcn_mfma_f32_16x16x32_bf16(a3[m], b1[n], acc[m][n], 0, 0, 0);
                }
        }
        __syncthreads();
    }
#pragma unroll
    for (int m = 0; m < 2; ++m)
#pragma unroll
        for (int n = 0; n < 2; ++n)
#pragma unroll
            for (int j = 0; j < 4; ++j) {
                int row = bm + wr + m * 16 + (lane >> 4) * 4 + j;
                int col = bn + wc + n * 16 + (lane & 15);
                D[(size_t)row * 4096 + h * 1024 + p * 512 + col] = acc[m][n][j];
            }
}

// ---- bisection: find tau with 32 <= #{v >= tau} <= 64 (wave-uniform result) ----
template<int NV>
__device__ __forceinline__ bool bisect_tau(const float (&v)[NV], float& tau_out, int& c_out) {
    float lo = v[0], hi = v[0];
#pragma unroll
    for (int i = 1; i < NV; ++i) { lo = fminf(lo, v[i]); hi = fmaxf(hi, v[i]); }
#pragma unroll
    for (int off = 1; off < 64; off <<= 1) {
        lo = fminf(lo, __shfl_xor(lo, off));
        hi = fmaxf(hi, __shfl_xor(hi, off));
    }
    float tau = 0.5f * (lo + hi);
    for (int it = 0; it < 24; ++it) {
        int cl = 0;
#pragma unroll
        for (int i = 0; i < NV; ++i) cl += (v[i] >= tau) ? 1 : 0;
#pragma unroll
        for (int off = 1; off < 64; off <<= 1) cl += __shfl_xor(cl, off);
        if (cl >= 32 && cl <= 64) { tau_out = tau; c_out = cl; return true; }
        if (cl < 32) hi = tau; else lo = tau;
        float nt = 0.5f * (lo + hi);
        if (nt == tau || nt == lo || nt == hi) break;   // bracket exhausted -> fallback
        tau = nt;
    }
    return false;
}

// ---- bitonic-64 across lanes, sort (v desc, n asc); pads sink ----
__device__ __forceinline__ void bitonic64(float& sv, int& sn, int lane) {
#pragma unroll
    for (int k = 2; k <= 64; k <<= 1) {
#pragma unroll
        for (int j = k >> 1; j >= 1; j >>= 1) {
            float ov = __shfl_xor(sv, j);
            int   on = __shfl_xor(sn, j);
            bool lower   = (lane & j) == 0;
            bool descseg = (lane & k) == 0;
            bool keepwin = (lower == descseg);
            bool iwin = (sv > ov) || (sv == ov && sn < on);
            if (keepwin != iwin) { sv = ov; sn = on; }
        }
    }
}

// ---------------- fused topk + gather: one block per token ----------------
__global__ __launch_bounds__(256) void k_topk_gather(const float* __restrict__ D,
                                                     const float* __restrict__ V,
                                                     float* __restrict__ out) {
    const int tid = threadIdx.x;
    const int wid = tid >> 6, lane = tid & 63;
    const int token = blockIdx.x;
    const int h = wid;
    __shared__ float s1[NHEAD][TK], s2[NHEAD][TK], wv[NHEAD][TK];
    __shared__ int   i1[NHEAD][TK], i2[NHEAD][TK], cc[NHEAD][TK];
    __shared__ float candV[NHEAD][64];
    __shared__ int   candN[NHEAD][64];
    __shared__ float wgt[128];
    __shared__ int   gidx[128];

    const size_t base = (size_t)token * 4096 + (size_t)h * 1024;
    float v1[8], v2[8];
#pragma unroll
    for (int i = 0; i < 8; ++i) {
        v1[i] = D[base + lane + (i << 6)];
        v2[i] = D[base + 512 + lane + (i << 6)];
    }

    // ---- select top-32 of v1 / v2 via bisect+compact+bitonic (fallback: extraction) ----
#pragma unroll
    for (int half = 0; half < 2; ++half) {
        float (&vv)[8] = half ? v2 : v1;
        float* sO = half ? &s2[h][0] : &s1[h][0];
        int*   iO = half ? &i2[h][0] : &i1[h][0];
        float tau; int c;
        if (bisect_tau<8>(vv, tau, c)) {
            int cum = 0;
#pragma unroll
            for (int i = 0; i < 8; ++i) {
                bool f = (vv[i] >= tau);
                unsigned long long bal = __ballot(f);
                int slot = cum + __popcll(bal & ((1ull << lane) - 1ull));
                if (f) { candV[h][slot] = vv[i]; candN[h][slot] = lane + (i << 6); }
                cum += __popcll(bal);
            }
            asm volatile("s_waitcnt lgkmcnt(0)" ::: "memory");
            float sv = (lane < c) ? candV[h][lane] : -INFINITY;
            int   sn = (lane < c) ? candN[h][lane] : 0x7FFFFFFF;
            bitonic64(sv, sn, lane);
            if (lane < TK) { sO[lane] = sv; iO[lane] = sn; }
        } else {
            // fallback: serial extraction (exact, rare)
            for (int it = 0; it < TK; ++it) {
                float bv = vv[0]; int bi = 0;
#pragma unroll
                for (int i = 1; i < 8; ++i) if (vv[i] > bv) { bv = vv[i]; bi = i; }
                int bn = lane + (bi << 6);
#pragma unroll
                for (int off = 1; off < 64; off <<= 1) {
                    float ov = __shfl_xor(bv, off);
                    int   on = __shfl_xor(bn, off);
                    if (ov > bv || (ov == bv && on < bn)) { bv = ov; bn = on; }
                }
#pragma unroll
                for (int i = 0; i < 8; ++i)
                    if (bn == lane + (i << 6)) vv[i] = -INFINITY;
                if (lane == 0) { sO[it] = bv; iO[it] = bn; }
            }
        }
    }

    // ---- combine: top-32 of 1024 pairwise sums, c-index tie-break, fused softmax ----
    float cv[16];
#pragma unroll
    for (int s = 0; s < 16; ++s) {
        int c = lane + (s << 6);
        cv[s] = s1[h][c >> 5] + s2[h][c & 31];
    }
    {
        float tau; int c;
        if (bisect_tau<16>(cv, tau, c)) {
            int cum = 0;
#pragma unroll
            for (int s = 0; s < 16; ++s) {
                bool f = (cv[s] >= tau);
                unsigned long long bal = __ballot(f);
                int slot = cum + __popcll(bal & ((1ull << lane) - 1ull));
                if (f) { candV[h][slot] = cv[s]; candN[h][slot] = lane + (s << 6); }
                cum += __popcll(bal);
            }
            asm volatile("s_waitcnt lgkmcnt(0)" ::: "memory");
            float sv = (lane < c) ? candV[h][lane] : -INFINITY;
            int   sn = (lane < c) ? candN[h][lane] : 0x7FFFFFFF;
            bitonic64(sv, sn, lane);
            float m = __shfl(sv, 0);
            float w = (lane < TK) ? expf(sv - m) : 0.0f;
            float sum = w;
#pragma unroll
            for (int off = 1; off < 64; off <<= 1) sum += __shfl_xor(sum, off);
            if (lane < TK) {
                wgt[h * TK + lane]  = w / sum;
                gidx[h * TK + lane] = i1[h][sn >> 5] * NKEY + i2[h][sn & 31];
            }
        } else {
            float m = 0.f, sum = 0.f;
            for (int it = 0; it < TK; ++it) {
                float bv = cv[0]; int bs = 0;
#pragma unroll
                for (int s = 1; s < 16; ++s) if (cv[s] > bv) { bv = cv[s]; bs = s; }
                int bc = lane + (bs << 6);
#pragma unroll
                for (int off = 1; off < 64; off <<= 1) {
                    float ov = __shfl_xor(bv, off);
                    int   oc = __shfl_xor(bc, off);
                    if (ov > bv || (ov == bv && oc < bc)) { bv = ov; bc = oc; }
                }
#pragma unroll
                for (int s = 0; s < 16; ++s)
                    if (bc == lane + (s << 6)) cv[s] = -INFINITY;
                if (it == 0) m = bv;
                float w = expf(bv - m);
                sum += w;
                if (lane == 0) { wv[h][it] = w; cc[h][it] = bc; }
            }
            if (lane < TK) {
                int c2 = cc[h][lane];
                wgt[h * TK + lane]  = wv[h][lane] / sum;
                gidx[h * TK + lane] = i1[h][c2 >> 5] * NKEY + i2[h][c2 & 31];
            }
        }
    }
    __syncthreads();

    // ---- phase 2: gather + weighted sum ----
    const int col = tid * 4;
    float4 acc = make_float4(0.f, 0.f, 0.f, 0.f);
#pragma unroll 8
    for (int j = 0; j < 128; ++j) {
        const float4 v = *(const float4*)(V + (size_t)gidx[j] * DIM + col);
        const float wj = wgt[j];
        acc.x = fmaf(wj, v.x, acc.x);
        acc.y = fmaf(wj, v.y, acc.y);
        acc.z = fmaf(wj, v.z, acc.z);
        acc.w = fmaf(wj, v.w, acc.w);
    }
    *(float4*)(out + (size_t)token * DIM + col) = acc;
}

extern "C" void kernel_launch(void* const* d_in, const int* in_sizes, int n_in,
                              void* d_out, int out_size, void* d_ws, size_t ws_size,
                              hipStream_t stream) {
    const float* x      = (const float*)d_in[0];
    const float* Wq     = (const float*)d_in[1];
    const float* gamma  = (const float*)d_in[2];
    const float* beta   = (const float*)d_in[3];
    const float* keys   = (const float*)d_in[4];
    const float* values = (const float*)d_in[5];

    char* w = (char*)d_ws;
    float* D = (float*)w;                          // 32 MB (first 8 MB alias q fp32; q dead before dots writes D)
    float* q = D;
    unsigned short* X1 = (unsigned short*)(w + ((size_t)34 << 20));
    unsigned short* X2 = (unsigned short*)(w + ((size_t)38 << 20));
    unsigned short* X3 = (unsigned short*)(w + ((size_t)42 << 20));
    unsigned short* W1 = (unsigned short*)(w + ((size_t)46 << 20));
    unsigned short* W2 = (unsigned short*)(w + ((size_t)48 << 20));
    unsigned short* W3 = (unsigned short*)(w + ((size_t)50 << 20));
    unsigned short* q1 = (unsigned short*)(w + ((size_t)52 << 20));
    unsigned short* q2 = (unsigned short*)(w + ((size_t)56 << 20));
    unsigned short* q3 = (unsigned short*)(w + ((size_t)60 << 20));
    unsigned short* K1 = (unsigned short*)(w + ((size_t)64 << 20));
    unsigned short* K2 = (unsigned short*)(w + ((size_t)65 << 20));
    unsigned short* K3 = (unsigned short*)(w + ((size_t)66 << 20));

    k_prep<<<3072, 256, 0, stream>>>(x, Wq, keys, X1, X2, X3, W1, W2, W3, K1, K2, K3);
    k_gemm<<<dim3(32, 16), 256, 0, stream>>>(X1, X2, X3, W1, W2, W3, q);
    k_ln<<<NTOK, 256, 0, stream>>>(q, gamma, beta, q1, q2, q3);
    k_dotsM<<<dim3(32, 8, 8), 256, 0, stream>>>(q1, q2, q3, K1, K2, K3, D);
    k_topk_gather<<<NTOK, 256, 0, stream>>>(D, values, (float*)d_out);
}